// Round 1
// baseline (422.123 us; speedup 1.0000x reference)
//
#include <hip/hip_runtime.h>
#include <stdint.h>

// Implicit-GEMM Gabor conv via bf16 MFMA.
// x[16,3,224,224] fp32 (48 single-ch images), w[512,1,25,25] fp32,
// stride 4, pad 12 -> out[16,3,512,56,56] fp32.
// Per image: D[512 x 3136] = W[512 x 625] . P[625 x 3136], K split as
// 25 ky-iterations of one 16x16x32 MFMA K-chunk (kx 0..24, padded to 32).
//
// V2: weights pre-converted ONCE to bf16 [ky][512][32] in d_ws; A-fragments
// loaded directly from global (coalesced 1024B/wave), register double-buffered.
// No w_lds, no per-ky __syncthreads -> barrier-free K loop.

typedef __attribute__((ext_vector_type(8))) short short8v;
typedef __attribute__((ext_vector_type(4))) short short4v;
typedef __attribute__((ext_vector_type(4))) float float4v;

namespace {
constexpr int H = 224, W = 224, OC = 512, KS = 25, ST = 4, PD = 12;
constexpr int HO = 56, WO = 56;
constexpr int TCH = 128;                 // channels per block
constexpr int TOY = 4;                   // output rows per block
constexpr int IR  = (TOY - 1) * ST + KS; // 37 staged input rows
constexpr int IC  = (WO - 1) * ST + 32;  // 252 staged input cols (covers kx-pad reads)
constexpr int ISTR = 260;                // LDS row stride (breaks pow2 banking)
constexpr int KXP = 32;                  // padded kx (K chunk)
constexpr int WSTR = 40;                 // fallback: w_lds per-channel stride
constexpr int CHT = OC / TCH;            // 4
constexpr int OYT = HO / TOY;            // 14
constexpr int NIMG = 48;
constexpr int NB = NIMG * CHT * OYT;     // 2688 blocks
constexpr size_t W2_BYTES = (size_t)KS * OC * KXP * sizeof(short); // 819200
}

__device__ __forceinline__ short f2bf(float f) {
    uint32_t u = __float_as_uint(f);
    u += 0x7fffu + ((u >> 16) & 1u);     // round-to-nearest-even
    return (short)(u >> 16);
}

// ---- one-time weight convert: fp32 [512][25][25] -> bf16 [ky][512][32] ----
__global__ void prep_w(const float* __restrict__ wt, short* __restrict__ w2) {
    int idx = blockIdx.x * 256 + threadIdx.x;
    if (idx >= KS * OC * KXP) return;
    int kx = idx & 31;
    int t  = idx >> 5;
    int ch = t & (OC - 1);
    int ky = t >> 9;
    float v = (kx < KS) ? wt[ch * (KS * KS) + ky * KS + kx] : 0.0f;
    w2[idx] = f2bf(v);
}

// ================= main kernel (V2: direct-global A, no barriers) ===========
__global__ __launch_bounds__(256, 2)
void gabor_mfma(const float* __restrict__ x,
                const short* __restrict__ w2,
                float* __restrict__ out) {
    __shared__ __align__(16) short in_lds[IR * ISTR];       // 18.8 KB

    const int tid = threadIdx.x;
    int bid = blockIdx.x;
    const int oyg = bid % OYT; bid /= OYT;
    const int cht = bid % CHT; bid /= CHT;
    const int img = bid;

    const int oy0 = oyg * TOY;
    const int cbase = cht * TCH;
    const int iy0 = oy0 * ST - PD;
    const float* __restrict__ xin = x + (size_t)img * H * W;

    // ---- stage input tile once (fp32 -> bf16 pairs, zero-fill OOB) ----
    constexpr int ICP = IC / 2;  // 126 column pairs
    for (int idx = tid; idx < IR * ICP; idx += 256) {
        int r = idx / ICP, cp = idx % ICP;
        int c = cp * 2;
        int iy = iy0 + r, ix = c - PD;
        float v0 = 0.0f, v1 = 0.0f;
        if ((unsigned)iy < (unsigned)H) {
            if ((unsigned)ix < (unsigned)W)       v0 = xin[iy * W + ix];
            if ((unsigned)(ix + 1) < (unsigned)W) v1 = xin[iy * W + ix + 1];
        }
        uint32_t pk = (uint32_t)(uint16_t)f2bf(v0) |
                      ((uint32_t)(uint16_t)f2bf(v1) << 16);
        *(uint32_t*)&in_lds[r * ISTR + c] = pk;   // 4B aligned (c even, ISTR even)
    }
    __syncthreads();

    // ---- wave / lane mapping ----
    const int lane = tid & 63;
    const int wid  = tid >> 6;
    const int wr = wid >> 1;        // channel half:   wr*64
    const int wc = wid & 1;         // oy row-pair:    oy0 + wc*2
    const int n = lane & 15;        // MFMA row/col index within 16-tile
    const int q = lane >> 4;        // quad -> k subchunk
    const int brow0 = (wc * 2 + (n >> 3)) * ST;      // input row base (add ky)
    const int bcol  = (n & 7) * ST + q * 8;          // input col base (add b*32)

    // A-fragment base in preconverted weights: [ky][512][32]
    // lane(n,q) of tile a reads ch = cbase + wr*64 + a*16 + n, kx = q*8..q*8+7
    const short* __restrict__ w2b =
        w2 + (size_t)(cbase + wr * 64 + n) * KXP + q * 8;

    float4v acc[4][7];
    #pragma unroll
    for (int a = 0; a < 4; ++a)
        #pragma unroll
        for (int b = 0; b < 7; ++b)
            acc[a][b] = (float4v)0.0f;

    short8v A0[4], A1[4];

    auto loadA = [&](int ky, short8v* dst) {
        #pragma unroll
        for (int a = 0; a < 4; ++a)
            dst[a] = *(const short8v*)(w2b + (size_t)ky * (OC * KXP) + a * (16 * KXP));
    };

    auto body = [&](int ky, const short8v* A) {
        const short* __restrict__ inp = &in_lds[(brow0 + ky) * ISTR + bcol];
        short8v Bv[7];
        #pragma unroll
        for (int b = 0; b < 7; ++b) {
            const short* p = inp + b * 32;           // 8B-aligned
            short4v lo = *(const short4v*)p;
            short4v hi = *(const short4v*)(p + 4);
            Bv[b] = __builtin_shufflevector(lo, hi, 0, 1, 2, 3, 4, 5, 6, 7);
        }
        #pragma unroll
        for (int b = 0; b < 7; ++b)
            #pragma unroll
            for (int a = 0; a < 4; ++a)
                acc[a][b] = __builtin_amdgcn_mfma_f32_16x16x32_bf16(A[a], Bv[b], acc[a][b], 0, 0, 0);
    };

    // ---- barrier-free K loop, A register-double-buffered (named bufs) ----
    loadA(0, A0);
    for (int kk = 0; kk < 12; ++kk) {
        const int ky = kk * 2;
        loadA(ky + 1, A1);
        body(ky, A0);
        loadA(ky + 2, A0);          // ky+2 <= 24 always
        body(ky + 1, A1);
    }
    body(24, A0);

    // ---- epilogue: D row = q*4 + reg (channel), col = n (position) ----
    const int oy = oy0 + wc * 2 + (n >> 3);
    const int chb = cbase + wr * 64 + q * 4;
    #pragma unroll
    for (int a = 0; a < 4; ++a) {
        #pragma unroll
        for (int b = 0; b < 7; ++b) {
            const int ch = chb + a * 16;
            const int ox = b * 8 + (n & 7);
            float* op = out + (((size_t)img * OC + ch) * HO + oy) * WO + ox;
            float4v v = acc[a][b];
            op[0]            = v[0];
            op[HO * WO]      = v[1];
            op[2 * HO * WO]  = v[2];
            op[3 * HO * WO]  = v[3];
        }
    }
}

// ================= fallback (previous verified kernel) ======================
__device__ __forceinline__ void stage_w_fb(short* dst, const float* __restrict__ wsrc,
                                           int ky, int tid) {
    #pragma unroll
    for (int i = 0; i < (TCH * KXP) / 256; ++i) {
        int idx = tid + i * 256;
        int ch = idx >> 5, kx = idx & 31;
        float v = (kx < KS) ? wsrc[ch * (KS * KS) + ky * KS + kx] : 0.0f;
        dst[ch * WSTR + kx] = f2bf(v);
    }
}

__global__ __launch_bounds__(256, 2)
void gabor_mfma_fb(const float* __restrict__ x,
                   const float* __restrict__ wt,
                   float* __restrict__ out) {
    __shared__ __align__(16) short in_lds[IR * ISTR];
    __shared__ __align__(16) short w_lds[2][TCH * WSTR];

    const int tid = threadIdx.x;
    int bid = blockIdx.x;
    const int oyg = bid % OYT; bid /= OYT;
    const int cht = bid % CHT; bid /= CHT;
    const int img = bid;

    const int oy0 = oyg * TOY;
    const int cbase = cht * TCH;
    const int iy0 = oy0 * ST - PD;
    const float* __restrict__ xin = x + (size_t)img * H * W;
    const float* __restrict__ wsrc = wt + (size_t)cbase * (KS * KS);

    for (int idx = tid; idx < IR * IC; idx += 256) {
        int r = idx / IC, c = idx % IC;
        int iy = iy0 + r, ix = c - PD;
        float v = 0.0f;
        if ((unsigned)iy < (unsigned)H && (unsigned)ix < (unsigned)W)
            v = xin[iy * W + ix];
        in_lds[r * ISTR + c] = f2bf(v);
    }
    stage_w_fb(w_lds[0], wsrc, 0, tid);
    __syncthreads();

    const int lane = tid & 63;
    const int wid  = tid >> 6;
    const int wr = wid >> 1;
    const int wc = wid & 1;
    const int n = lane & 15;
    const int q = lane >> 4;
    const int brow0 = (wc * 2 + (n >> 3)) * ST;
    const int bcol  = (n & 7) * ST + q * 8;
    const int awoff = (wr * 64 + n) * WSTR + q * 8;

    float4v acc[4][7];
    #pragma unroll
    for (int a = 0; a < 4; ++a)
        #pragma unroll
        for (int b = 0; b < 7; ++b)
            acc[a][b] = (float4v)0.0f;

    for (int ky = 0; ky < KS; ++ky) {
        const int cur = ky & 1;
        if (ky + 1 < KS) stage_w_fb(w_lds[cur ^ 1], wsrc, ky + 1, tid);

        const short* __restrict__ inp = &in_lds[(brow0 + ky) * ISTR + bcol];
        short8v Bv[7];
        #pragma unroll
        for (int b = 0; b < 7; ++b) {
            const short* p = inp + b * 32;
            short4v lo = *(const short4v*)p;
            short4v hi = *(const short4v*)(p + 4);
            Bv[b] = __builtin_shufflevector(lo, hi, 0, 1, 2, 3, 4, 5, 6, 7);
        }
        const short* __restrict__ wp = &w_lds[cur][awoff];
        #pragma unroll
        for (int a = 0; a < 4; ++a) {
            short8v A = *(const short8v*)(wp + a * 16 * WSTR);
            #pragma unroll
            for (int b = 0; b < 7; ++b)
                acc[a][b] = __builtin_amdgcn_mfma_f32_16x16x32_bf16(A, Bv[b], acc[a][b], 0, 0, 0);
        }
        __syncthreads();
    }

    const int oy = oy0 + wc * 2 + (n >> 3);
    const int chb = cbase + wr * 64 + q * 4;
    #pragma unroll
    for (int a = 0; a < 4; ++a) {
        #pragma unroll
        for (int b = 0; b < 7; ++b) {
            const int ch = chb + a * 16;
            const int ox = b * 8 + (n & 7);
            float* op = out + (((size_t)img * OC + ch) * HO + oy) * WO + ox;
            float4v v = acc[a][b];
            op[0]            = v[0];
            op[HO * WO]      = v[1];
            op[2 * HO * WO]  = v[2];
            op[3 * HO * WO]  = v[3];
        }
    }
}

extern "C" void kernel_launch(void* const* d_in, const int* in_sizes, int n_in,
                              void* d_out, int out_size, void* d_ws, size_t ws_size,
                              hipStream_t stream) {
    const float* x  = (const float*)d_in[0];   // [16,3,224,224]
    const float* wt = (const float*)d_in[1];   // [512,1,25,25]
    float* out = (float*)d_out;                // [16,3,512,56,56]
    (void)in_sizes; (void)n_in; (void)out_size;

    if (d_ws != nullptr && ws_size >= W2_BYTES) {
        short* w2 = (short*)d_ws;
        const int prep_total = KS * OC * KXP;
        prep_w<<<(prep_total + 255) / 256, 256, 0, stream>>>(wt, w2);
        gabor_mfma<<<NB, 256, 0, stream>>>(x, w2, out);
    } else {
        gabor_mfma_fb<<<NB, 256, 0, stream>>>(x, wt, out);
    }
}

// Round 2
// 378.739 us; speedup vs baseline: 1.1145x; 1.1145x over previous
//
#include <hip/hip_runtime.h>
#include <stdint.h>

// Implicit-GEMM Gabor conv via bf16 MFMA.
// x[16,3,224,224] fp32 (48 single-ch images), w[512,1,25,25] fp32,
// stride 4, pad 12 -> out[16,3,512,56,56] fp32.
//
// V3: x pre-converted once to zero-padded bf16 [48][248][256] in d_ws;
// input staging = linear global_load_lds (width 16, no VALU, no branches).
// Weights pre-converted once to bf16 [ky][512][32].
// K-loop fully unrolled; A and B fragments register double-buffered across ky
// (loads for ky+1 in flight during ky's MFMAs). XCD-chunked block swizzle.

typedef __attribute__((ext_vector_type(8))) short short8v;
typedef __attribute__((ext_vector_type(4))) short short4v;
typedef __attribute__((ext_vector_type(4))) float float4v;

namespace {
constexpr int H = 224, W = 224, OC = 512, KS = 25, ST = 4, PD = 12;
constexpr int HO = 56, WO = 56;
constexpr int TCH = 128;                 // channels per block
constexpr int TOY = 4;                   // output rows per block
constexpr int IR  = (TOY - 1) * ST + KS; // 37 staged input rows
constexpr int IRP = 38;                  // padded to even chunk count
constexpr int ISTR = 256;                // LDS row stride == padded image width
constexpr int KXP = 32;                  // padded kx (K chunk)
constexpr int CHT = OC / TCH;            // 4
constexpr int OYT = HO / TOY;            // 14
constexpr int NIMG = 48;
constexpr int NB = NIMG * CHT * OYT;     // 2688 blocks (divisible by 8)
constexpr int XPH = 248, XPW = 256;      // padded bf16 image dims
constexpr size_t W2_BYTES = (size_t)KS * OC * KXP * sizeof(short);     // 819200
constexpr size_t XP_BYTES = (size_t)NIMG * XPH * XPW * sizeof(short);  // 6094848
constexpr size_t WS_NEED  = W2_BYTES + XP_BYTES;
// fallback-kernel constants
constexpr int IC  = (WO - 1) * ST + 32;  // 252
constexpr int ISTR_FB = 260;
constexpr int WSTR = 40;
}

__device__ __forceinline__ short f2bf(float f) {
    uint32_t u = __float_as_uint(f);
    u += 0x7fffu + ((u >> 16) & 1u);     // round-to-nearest-even
    return (short)(u >> 16);
}

__device__ __forceinline__ void gload_lds16(const void* gsrc, void* ldst) {
    __builtin_amdgcn_global_load_lds(
        (const __attribute__((address_space(1))) uint32_t*)gsrc,
        (__attribute__((address_space(3))) uint32_t*)ldst,
        16, 0, 0);
}

// ---- one-time weight convert: fp32 [512][25][25] -> bf16 [ky][512][32] ----
__global__ void prep_w(const float* __restrict__ wt, short* __restrict__ w2) {
    int idx = blockIdx.x * 256 + threadIdx.x;
    if (idx >= KS * OC * KXP) return;
    int kx = idx & 31;
    int t  = idx >> 5;
    int ch = t & (OC - 1);
    int ky = t >> 9;
    float v = (kx < KS) ? wt[ch * (KS * KS) + ky * KS + kx] : 0.0f;
    w2[idx] = f2bf(v);
}

// ---- one-time x convert: fp32 [48][224][224] -> bf16 padded [48][248][256] ----
// padded row g <-> iy = g - 12; padded col c <-> ix = c - 12; OOB = 0.
__global__ void prep_x(const float* __restrict__ x, short* __restrict__ xp) {
    int idx = blockIdx.x * 256 + threadIdx.x;
    constexpr int total = NIMG * XPH * (XPW / 2);
    if (idx >= total) return;
    int cp  = idx & (XPW / 2 - 1);
    int t   = idx >> 7;
    int g   = t % XPH;
    int img = t / XPH;
    int c = cp * 2;
    int iy = g - PD, ix = c - PD;
    float v0 = 0.0f, v1 = 0.0f;
    if ((unsigned)iy < (unsigned)H) {
        const float* row = x + ((size_t)img * H + iy) * W;
        if ((unsigned)ix < (unsigned)W)       v0 = row[ix];
        if ((unsigned)(ix + 1) < (unsigned)W) v1 = row[ix + 1];
    }
    uint32_t pk = (uint32_t)(uint16_t)f2bf(v0) |
                  ((uint32_t)(uint16_t)f2bf(v1) << 16);
    *(uint32_t*)&xp[((size_t)img * XPH + g) * XPW + c] = pk;
}

// ================= main kernel (V3) =========================================
__global__ __launch_bounds__(256, 2)
void gabor_mfma(const short* __restrict__ w2,
                const short* __restrict__ xp,
                float* __restrict__ out) {
    __shared__ __align__(16) short in_lds[IRP * ISTR];   // 19456 B

    const int tid = threadIdx.x;
    // XCD-chunked swizzle (bijective: NB % 8 == 0)
    int bid = (blockIdx.x % 8) * (NB / 8) + blockIdx.x / 8;
    const int oyg = bid % OYT; bid /= OYT;
    const int cht = bid % CHT; bid /= CHT;
    const int img = bid;

    const int oy0 = oyg * TOY;
    const int cbase = cht * TCH;

    // ---- async stage: 38 padded rows starting at g0 = oy0*ST, linear copy ----
    const char* xpb = (const char*)(xp + ((size_t)img * XPH + oy0 * ST) * XPW);
    constexpr int CHUNKS = IRP * ISTR * 2 / 16;  // 1216 (rounds wave-uniform)
    for (int c = tid; c < CHUNKS; c += 256)
        gload_lds16(xpb + (size_t)c * 16, (char*)in_lds + c * 16);

    // ---- wave / lane mapping ----
    const int lane = tid & 63;
    const int wid  = tid >> 6;
    const int wr = wid >> 1;        // channel half:   wr*64
    const int wc = wid & 1;         // oy row-pair:    oy0 + wc*2
    const int n = lane & 15;        // MFMA row/col index within 16-tile
    const int q = lane >> 4;        // quad -> k subchunk
    const int brow0 = (wc * 2 + (n >> 3)) * ST;
    const int bcol  = (n & 7) * ST + q * 8;

    const short* __restrict__ w2b =
        w2 + (size_t)(cbase + wr * 64 + n) * KXP + q * 8;

    short8v A0[4], A1[4], B0[7], B1[7];

    // prologue A(0): global, independent of LDS -> issue before barrier
    #pragma unroll
    for (int a = 0; a < 4; ++a)
        A0[a] = *(const short8v*)(w2b + a * (16 * KXP));

    __syncthreads();   // drains staging (vmcnt) + barrier

    const short* __restrict__ inb = &in_lds[brow0 * ISTR + bcol];

    float4v acc[4][7];
    #pragma unroll
    for (int a = 0; a < 4; ++a)
        #pragma unroll
        for (int b = 0; b < 7; ++b)
            acc[a][b] = (float4v)0.0f;

    auto loadB = [&](int ky, short8v* Bd) {
        const short* p = inb + ky * ISTR;
        #pragma unroll
        for (int b = 0; b < 7; ++b) {
            short4v lo = *(const short4v*)(p + b * 32);      // 8B-aligned
            short4v hi = *(const short4v*)(p + b * 32 + 4);
            Bd[b] = __builtin_shufflevector(lo, hi, 0, 1, 2, 3, 4, 5, 6, 7);
        }
    };
    auto loadA = [&](int ky, short8v* Ad) {
        const short* p = w2b + (size_t)ky * (OC * KXP);
        #pragma unroll
        for (int a = 0; a < 4; ++a)
            Ad[a] = *(const short8v*)(p + a * (16 * KXP));
    };
    auto mma = [&](const short8v* Av, const short8v* Bv) {
        #pragma unroll
        for (int b = 0; b < 7; ++b)
            #pragma unroll
            for (int a = 0; a < 4; ++a)
                acc[a][b] = __builtin_amdgcn_mfma_f32_16x16x32_bf16(Av[a], Bv[b], acc[a][b], 0, 0, 0);
    };

    // ---- fully-unrolled K loop, A+B register double-buffered across ky ----
    loadB(0, B0);
    #pragma unroll
    for (int ky = 0; ky < KS; ++ky) {
        if (ky + 1 < KS) {
            loadB(ky + 1, (ky & 1) ? B0 : B1);
            loadA(ky + 1, (ky & 1) ? A0 : A1);
        }
        mma((ky & 1) ? A1 : A0, (ky & 1) ? B1 : B0);
    }

    // ---- epilogue: D row = q*4 + reg (channel), col = n (position) ----
    const int oy = oy0 + wc * 2 + (n >> 3);
    const int chb = cbase + wr * 64 + q * 4;
    #pragma unroll
    for (int a = 0; a < 4; ++a) {
        #pragma unroll
        for (int b = 0; b < 7; ++b) {
            const int ch = chb + a * 16;
            const int ox = b * 8 + (n & 7);
            float* op = out + (((size_t)img * OC + ch) * HO + oy) * WO + ox;
            float4v v = acc[a][b];
            op[0]            = v[0];
            op[HO * WO]      = v[1];
            op[2 * HO * WO]  = v[2];
            op[3 * HO * WO]  = v[3];
        }
    }
}

// ================= fallback (previous verified kernel) ======================
__device__ __forceinline__ void stage_w_fb(short* dst, const float* __restrict__ wsrc,
                                           int ky, int tid) {
    #pragma unroll
    for (int i = 0; i < (TCH * KXP) / 256; ++i) {
        int idx = tid + i * 256;
        int ch = idx >> 5, kx = idx & 31;
        float v = (kx < KS) ? wsrc[ch * (KS * KS) + ky * KS + kx] : 0.0f;
        dst[ch * WSTR + kx] = f2bf(v);
    }
}

__global__ __launch_bounds__(256, 2)
void gabor_mfma_fb(const float* __restrict__ x,
                   const float* __restrict__ wt,
                   float* __restrict__ out) {
    __shared__ __align__(16) short in_lds[IR * ISTR_FB];
    __shared__ __align__(16) short w_lds[2][TCH * WSTR];

    const int tid = threadIdx.x;
    int bid = blockIdx.x;
    const int oyg = bid % OYT; bid /= OYT;
    const int cht = bid % CHT; bid /= CHT;
    const int img = bid;

    const int oy0 = oyg * TOY;
    const int cbase = cht * TCH;
    const int iy0 = oy0 * ST - PD;
    const float* __restrict__ xin = x + (size_t)img * H * W;
    const float* __restrict__ wsrc = wt + (size_t)cbase * (KS * KS);

    for (int idx = tid; idx < IR * IC; idx += 256) {
        int r = idx / IC, c = idx % IC;
        int iy = iy0 + r, ix = c - PD;
        float v = 0.0f;
        if ((unsigned)iy < (unsigned)H && (unsigned)ix < (unsigned)W)
            v = xin[iy * W + ix];
        in_lds[r * ISTR_FB + c] = f2bf(v);
    }
    stage_w_fb(w_lds[0], wsrc, 0, tid);
    __syncthreads();

    const int lane = tid & 63;
    const int wid  = tid >> 6;
    const int wr = wid >> 1;
    const int wc = wid & 1;
    const int n = lane & 15;
    const int q = lane >> 4;
    const int brow0 = (wc * 2 + (n >> 3)) * ST;
    const int bcol  = (n & 7) * ST + q * 8;
    const int awoff = (wr * 64 + n) * WSTR + q * 8;

    float4v acc[4][7];
    #pragma unroll
    for (int a = 0; a < 4; ++a)
        #pragma unroll
        for (int b = 0; b < 7; ++b)
            acc[a][b] = (float4v)0.0f;

    for (int ky = 0; ky < KS; ++ky) {
        const int cur = ky & 1;
        if (ky + 1 < KS) stage_w_fb(w_lds[cur ^ 1], wsrc, ky + 1, tid);

        const short* __restrict__ inp = &in_lds[(brow0 + ky) * ISTR_FB + bcol];
        short8v Bv[7];
        #pragma unroll
        for (int b = 0; b < 7; ++b) {
            const short* p = inp + b * 32;
            short4v lo = *(const short4v*)p;
            short4v hi = *(const short4v*)(p + 4);
            Bv[b] = __builtin_shufflevector(lo, hi, 0, 1, 2, 3, 4, 5, 6, 7);
        }
        const short* __restrict__ wp = &w_lds[cur][awoff];
        #pragma unroll
        for (int a = 0; a < 4; ++a) {
            short8v A = *(const short8v*)(wp + a * 16 * WSTR);
            #pragma unroll
            for (int b = 0; b < 7; ++b)
                acc[a][b] = __builtin_amdgcn_mfma_f32_16x16x32_bf16(A, Bv[b], acc[a][b], 0, 0, 0);
        }
        __syncthreads();
    }

    const int oy = oy0 + wc * 2 + (n >> 3);
    const int chb = cbase + wr * 64 + q * 4;
    #pragma unroll
    for (int a = 0; a < 4; ++a) {
        #pragma unroll
        for (int b = 0; b < 7; ++b) {
            const int ch = chb + a * 16;
            const int ox = b * 8 + (n & 7);
            float* op = out + (((size_t)img * OC + ch) * HO + oy) * WO + ox;
            float4v v = acc[a][b];
            op[0]            = v[0];
            op[HO * WO]      = v[1];
            op[2 * HO * WO]  = v[2];
            op[3 * HO * WO]  = v[3];
        }
    }
}

extern "C" void kernel_launch(void* const* d_in, const int* in_sizes, int n_in,
                              void* d_out, int out_size, void* d_ws, size_t ws_size,
                              hipStream_t stream) {
    const float* x  = (const float*)d_in[0];   // [16,3,224,224]
    const float* wt = (const float*)d_in[1];   // [512,1,25,25]
    float* out = (float*)d_out;                // [16,3,512,56,56]
    (void)in_sizes; (void)n_in; (void)out_size;

    if (d_ws != nullptr && ws_size >= WS_NEED) {
        short* w2 = (short*)d_ws;
        short* xp = (short*)((char*)d_ws + W2_BYTES);
        const int wtot = KS * OC * KXP;
        const int xtot = NIMG * XPH * (XPW / 2);
        prep_w<<<(wtot + 255) / 256, 256, 0, stream>>>(wt, w2);
        prep_x<<<(xtot + 255) / 256, 256, 0, stream>>>(x, xp);
        gabor_mfma<<<NB, 256, 0, stream>>>(w2, xp, out);
    } else {
        gabor_mfma_fb<<<NB, 256, 0, stream>>>(x, wt, out);
    }
}